// Round 3
// baseline (419.865 us; speedup 1.0000x reference)
//
#include <hip/hip_runtime.h>

#define ALPHA 0.9f
#define BETA  0.8f
#define XS 36960   // padded row stride for x and w1p

typedef _Float16 f16;
typedef _Float16 f16x8 __attribute__((ext_vector_type(8)));
typedef float f32x4 __attribute__((ext_vector_type(4)));

// 16B load at only-4B-known alignment (rows of width 55/26 floats can't be
// 16B aligned). Backend emits wide unaligned global loads; worst case it
// splits into dwords -- same addresses either way.
struct F4 { float x, y, z, w; };   // alignof = 4

// ---------------------------------------------------------------------------
// state: 128x3x224x224  conv1 32x3x8x8 s4 -> f1 (fp32) 128x32x55x55
// f1 -> conv2 64x32x4x4 s2 -> f2 (fp32) 128x64x26x26
// f2 -> conv3 64x64x3x3 s1 -> x rows fp32 (36864 + 90 history, pad 36960)
// Convs: split-f16 MFMA (hi+lo, 3 MFMAs/product, fp32-quality: absmax 0.0).
// r11: unified direct conv, register double-buffered software pipeline.
//   Diagnosis r10: VGPR_Count=40 -> compiler serialized the gather (MLP~1),
//   latency-bound at 2.2 TB/s regardless of barriers. Fix: named 2-deep
//   register buffers force ~8-12 loads in flight per wave; no LDS, no
//   barriers; A-fragments straight from global (L1/L2-resident weights).
// r12: identical to r11 resubmission (round 2 was GPUAcquisitionTimeout,
//   kernel never ran).
// ---------------------------------------------------------------------------

// Split conv weights into f16 hi/lo pairs; conv3 padded [oc][c][kh][4]
// (kw=3 -> 0). Repack w2 (256x128) -> w2q[k4][j] float4 columns.
__global__ __launch_bounds__(256) void prep_weights_kernel(
    const float* __restrict__ cw1, const float* __restrict__ cw2,
    const float* __restrict__ cw3, const float* __restrict__ w2,
    f16* __restrict__ w1h, f16* __restrict__ w1l,
    f16* __restrict__ w2h, f16* __restrict__ w2l,
    f16* __restrict__ w3h, f16* __restrict__ w3l,
    float* __restrict__ w2q) {
  int i = blockIdx.x * 256 + threadIdx.x;   // grid covers 49152
  if (i < 6144)  { float v = cw1[i]; f16 h = (f16)v; w1h[i] = h; w1l[i] = (f16)(v - (float)h); }
  if (i < 32768) { float v = cw2[i]; f16 h = (f16)v; w2h[i] = h; w2l[i] = (f16)(v - (float)h); }
  if (i < 49152) {
    int oc = i / 768, r = i % 768;
    int c = r / 12, rr = r % 12, kh = rr >> 2, kw = rr & 3;
    float v = (kw < 3) ? cw3[oc * 576 + c * 9 + kh * 3 + kw] : 0.f;
    f16 h = (f16)v; w3h[i] = h; w3l[i] = (f16)(v - (float)h);
  }
  if (i < 32768) {   // w2[j][k] -> w2q[(k4*256 + j)*4 + e]
    int j = i >> 7, k = i & 127;
    w2q[((k >> 2) * 256 + j) * 4 + (k & 3)] = w2[i];
  }
}

// Copy w1 (128 x 36954) into padded rows (128 x 36960), zero tail.
__global__ __launch_bounds__(256) void pad_w1_kernel(
    const float* __restrict__ w1, float* __restrict__ w1p) {
  int i = blockIdx.x * 256 + threadIdx.x;   // float2 slots: 128 * 18480
  if (i < 128 * 18480) {
    int j = i / 18480, c = i - j * 18480;
    float2 v;
    if (c < 18477) v = *(const float2*)&w1[(size_t)j * 36954 + c * 2];
    else v = make_float2(0.f, 0.f);
    *(float2*)&w1p[(size_t)j * XS + c * 2] = v;
  }
}

// ---------------------------------------------------------------------------
// Unified direct conv. GEMM view: C[oc][pos] = W[oc][K]*Im[K][pos],
// K = IC*KH*KWP (KWP-padded filter rows, kw >= KWV compile-time-zeroed).
// 16x16x32 MFMA layouts (HW-verified): A[m=lane&15][k=quad*8+j],
// B[k=quad*8+j][n=lane&15], C col=lane&15 row=quad*4+reg.
// Per wave: 2 m-tiles x 2 n-tiles. Per kt: 4 A f16x8 loads (per-lane direct
// from global, 16B aligned) + 4 B gathers (2 per n-tile: lane's 8 k's are
// 2 filter-row segments of 4, or one 8-float run when KWP==8).
// Software pipeline: LOAD(kt+1) issued before COMPUTE(kt); named [2] register
// buffers keep loads in flight (fully unrolled -> all indices compile-time).
// ---------------------------------------------------------------------------
template<int IC, int KH, int KWP, int KWV, int S, int IH, int IW,
         int OW, int OHW, int OC, int NPB, bool OUT_X>
__global__ __launch_bounds__(256) void direct_conv_kernel(
    const float* __restrict__ in, const f16* __restrict__ wh,
    const f16* __restrict__ wl, const float* __restrict__ bias,
    float* __restrict__ out) {
  constexpr int K = IC * KH * KWP;      // 192 / 512 / 768
  constexpr int KCH = K / 32;           // 6 / 16 / 24
  constexpr int MTILES = OC / 16;       // 2 / 4
  constexpr int WOC = MTILES / 2;       // 1 / 2
  constexpr bool AL16 = (IW % 4 == 0) && (S % 4 == 0);   // conv1 only
  constexpr int EM = (KWP == 4) ? 3 : 7;                 // kw mask within elem

  const int n = blockIdx.y;
  const int pos0 = blockIdx.x * NPB;
  const int t = threadIdx.x;
  const int w = t >> 6, lane = t & 63, quad = lane >> 4, l16 = lane & 15;
  const int woc  = (WOC == 1) ? 0 : (w & 1);
  const int wpos = (WOC == 1) ? w : (w >> 1);
  const float* __restrict__ inb = in + (size_t)n * IC * IH * IW;

  int posv[2], ohS[2], owS[2];
#pragma unroll
  for (int ntl = 0; ntl < 2; ++ntl) {
    int pos = pos0 + (wpos * 2 + ntl) * 16 + l16;
    posv[ntl] = pos;
    if (pos > OHW - 1) pos = OHW - 1;    // clamp (store masked later)
    int oh = pos / OW, ow = pos - oh * OW;
    ohS[ntl] = oh * S; owS[ntl] = ow * S;
  }
  const f16* __restrict__ whp0 = wh + (size_t)((woc * 2 + 0) * 16 + l16) * K;
  const f16* __restrict__ whp1 = wh + (size_t)((woc * 2 + 1) * 16 + l16) * K;
  const f16* __restrict__ wlp0 = wl + (size_t)((woc * 2 + 0) * 16 + l16) * K;
  const f16* __restrict__ wlp1 = wl + (size_t)((woc * 2 + 1) * 16 + l16) * K;

  f32x4 acc[2][2] = {};

  // 2-deep register pipeline buffers (all indices compile-time via unroll)
  f16x8 rah0[2], rah1[2], ral0[2], ral1[2];
  float rb[2][2][8];   // [buf][ntl][elem]

  auto LOAD = [&](int kt, int buf) {
    rah0[buf] = *(const f16x8*)&whp0[kt * 32 + quad * 8];
    rah1[buf] = *(const f16x8*)&whp1[kt * 32 + quad * 8];
    ral0[buf] = *(const f16x8*)&wlp0[kt * 32 + quad * 8];
    ral1[buf] = *(const f16x8*)&wlp1[kt * 32 + quad * 8];
#pragma unroll
    for (int ntl = 0; ntl < 2; ++ntl)
#pragma unroll
      for (int half = 0; half < 2; ++half) {
        int kk = kt * 32 + quad * 8 + half * 4;
        int row = kk / KWP, kw0 = kk % KWP;        // pow2 -> shifts
        int c = row / KH, kh = row - c * KH;
        const float* p = inb + ((size_t)c * IH + ohS[ntl] + kh) * IW
                             + owS[ntl] + kw0;
        if constexpr (AL16) {
          float4 v = *(const float4*)p;
          rb[buf][ntl][half * 4 + 0] = v.x;
          rb[buf][ntl][half * 4 + 1] = v.y;
          rb[buf][ntl][half * 4 + 2] = v.z;
          rb[buf][ntl][half * 4 + 3] = v.w;
        } else {
          F4 v = *(const F4*)p;
          rb[buf][ntl][half * 4 + 0] = v.x;
          rb[buf][ntl][half * 4 + 1] = v.y;
          rb[buf][ntl][half * 4 + 2] = v.z;
          rb[buf][ntl][half * 4 + 3] = v.w;
        }
      }
  };

  auto COMPUTE = [&](int buf) {
    f16x8 bh0, bl0, bh1, bl1;
#pragma unroll
    for (int e = 0; e < 8; ++e) {
      float v0 = ((e & EM) >= KWV) ? 0.f : rb[buf][0][e];
      f16 h0 = (f16)v0;
      bh0[e] = h0; bl0[e] = (f16)(v0 - (float)h0);
      float v1 = ((e & EM) >= KWV) ? 0.f : rb[buf][1][e];
      f16 h1 = (f16)v1;
      bh1[e] = h1; bl1[e] = (f16)(v1 - (float)h1);
    }
    acc[0][0] = __builtin_amdgcn_mfma_f32_16x16x32_f16(rah0[buf], bh0, acc[0][0], 0, 0, 0);
    acc[0][0] = __builtin_amdgcn_mfma_f32_16x16x32_f16(rah0[buf], bl0, acc[0][0], 0, 0, 0);
    acc[0][0] = __builtin_amdgcn_mfma_f32_16x16x32_f16(ral0[buf], bh0, acc[0][0], 0, 0, 0);
    acc[1][0] = __builtin_amdgcn_mfma_f32_16x16x32_f16(rah1[buf], bh0, acc[1][0], 0, 0, 0);
    acc[1][0] = __builtin_amdgcn_mfma_f32_16x16x32_f16(rah1[buf], bl0, acc[1][0], 0, 0, 0);
    acc[1][0] = __builtin_amdgcn_mfma_f32_16x16x32_f16(ral1[buf], bh0, acc[1][0], 0, 0, 0);
    acc[0][1] = __builtin_amdgcn_mfma_f32_16x16x32_f16(rah0[buf], bh1, acc[0][1], 0, 0, 0);
    acc[0][1] = __builtin_amdgcn_mfma_f32_16x16x32_f16(rah0[buf], bl1, acc[0][1], 0, 0, 0);
    acc[0][1] = __builtin_amdgcn_mfma_f32_16x16x32_f16(ral0[buf], bh1, acc[0][1], 0, 0, 0);
    acc[1][1] = __builtin_amdgcn_mfma_f32_16x16x32_f16(rah1[buf], bh1, acc[1][1], 0, 0, 0);
    acc[1][1] = __builtin_amdgcn_mfma_f32_16x16x32_f16(rah1[buf], bl1, acc[1][1], 0, 0, 0);
    acc[1][1] = __builtin_amdgcn_mfma_f32_16x16x32_f16(ral1[buf], bh1, acc[1][1], 0, 0, 0);
  };

  LOAD(0, 0);
#pragma unroll
  for (int kt = 0; kt < KCH - 1; ++kt) {
    LOAD(kt + 1, (kt + 1) & 1);
    COMPUTE(kt & 1);
  }
  COMPUTE((KCH - 1) & 1);

#pragma unroll
  for (int mtl = 0; mtl < 2; ++mtl)
#pragma unroll
    for (int ntl = 0; ntl < 2; ++ntl)
#pragma unroll
      for (int r = 0; r < 4; ++r) {
        int oc  = (woc * 2 + mtl) * 16 + quad * 4 + r;
        int pos = posv[ntl];
        if (pos < OHW) {
          float v = acc[mtl][ntl][r] + bias[oc];
          v = v > 0.f ? v : 0.f;
          if (OUT_X)
            out[(size_t)n * XS + oc * OHW + pos] = v;
          else
            out[((size_t)n * OC + oc) * OHW + pos] = v;
        }
      }
}

// history -> x[:, 36864:36954], zero the pad to 36960
__global__ __launch_bounds__(256) void histpack_kernel(
    const float* __restrict__ h, float* __restrict__ x) {
  int i = blockIdx.x * 256 + threadIdx.x;
  if (i < 128 * 96) {
    int n = i / 96, k = i % 96;
    x[(size_t)n * XS + 36864 + k] = (k < 90) ? h[n * 90 + k] : 0.f;
  }
}

// FC1 (fp32): register-blocked split-K GEMM, 128b x 128j tile per block,
// thread owns 8x8 interleaved sub-tile. P[kt][b][j] deterministic partials.
#define FC1_KT 289
__global__ __launch_bounds__(256) void fc1_kernel(
    const float* __restrict__ x, const float* __restrict__ w1p,
    float* __restrict__ P) {
  int kt = blockIdx.x;        // 0..288
  int t  = threadIdx.x;
  int bq = t & 15, jq = t >> 4;
  __shared__ float xs[128 * 36];
  __shared__ float wsm[128 * 36];
  float acc[8][8];
#pragma unroll
  for (int bb = 0; bb < 8; ++bb)
#pragma unroll
    for (int jj = 0; jj < 8; ++jj) acc[bb][jj] = 0.f;

  int cs = t & 7;          // float4 column for staging (0..7)
  int rs = t >> 3;         // row base for staging (0..31), 4 passes
#pragma unroll 1
  for (int s = 0; s < 4; ++s) {
    int k0 = kt * 128 + s * 32;
    __syncthreads();
#pragma unroll
    for (int p = 0; p < 4; ++p) {
      int r = rs + p * 32;
      int gk = k0 + cs * 4;
      float4 xv, wv;
      if (gk < 36954) {
        xv = *(const float4*)&x[(size_t)r * XS + gk];
        wv = *(const float4*)&w1p[(size_t)r * XS + gk];
      } else {
        xv = make_float4(0.f, 0.f, 0.f, 0.f);
        wv = make_float4(0.f, 0.f, 0.f, 0.f);
      }
      *(float4*)&xs[r * 36 + cs * 4] = xv;
      *(float4*)&wsm[r * 36 + cs * 4] = wv;
    }
    __syncthreads();
#pragma unroll 1
    for (int kk = 0; kk < 32; kk += 4) {
      float4 xv[8], wv[8];
#pragma unroll
      for (int i = 0; i < 8; ++i)
        xv[i] = *(const float4*)&xs[(bq + 16 * i) * 36 + kk];
#pragma unroll
      for (int i = 0; i < 8; ++i)
        wv[i] = *(const float4*)&wsm[(jq + 16 * i) * 36 + kk];
#pragma unroll
      for (int bb = 0; bb < 8; ++bb)
#pragma unroll
        for (int jj = 0; jj < 8; ++jj) {
          acc[bb][jj] = fmaf(xv[bb].x, wv[jj].x, acc[bb][jj]);
          acc[bb][jj] = fmaf(xv[bb].y, wv[jj].y, acc[bb][jj]);
          acc[bb][jj] = fmaf(xv[bb].z, wv[jj].z, acc[bb][jj]);
          acc[bb][jj] = fmaf(xv[bb].w, wv[jj].w, acc[bb][jj]);
        }
    }
  }
  float* Pb = P + (size_t)kt * 16384;
#pragma unroll
  for (int bb = 0; bb < 8; ++bb)
#pragma unroll
    for (int jj = 0; jj < 8; ++jj)
      Pb[(bq + 16 * bb) * 128 + jq + 16 * jj] = acc[bb][jj];
}

// Reduce P over kt: h1s[b][j] = sum_kt P[kt][b][j] + b1[j].
__global__ __launch_bounds__(256) void reduce_p_kernel(
    const float* __restrict__ P, const float* __restrict__ b1,
    float* __restrict__ h1s) {
  int idx = blockIdx.x * 256 + threadIdx.x;   // 0..16383
  int j = idx & 127;
  float a0 = 0.f, a1 = 0.f, a2 = 0.f, a3 = 0.f;
  int kt = 0;
#pragma unroll 2
  for (; kt + 3 < FC1_KT; kt += 4) {
    a0 += P[(size_t)(kt + 0) * 16384 + idx];
    a1 += P[(size_t)(kt + 1) * 16384 + idx];
    a2 += P[(size_t)(kt + 2) * 16384 + idx];
    a3 += P[(size_t)(kt + 3) * 16384 + idx];
  }
  for (; kt < FC1_KT; ++kt) a0 += P[(size_t)kt * 16384 + idx];
  h1s[idx] = ((a0 + a1) + (a2 + a3)) + b1[j];
}

// Recurrence: one block per batch row. w2 column in VGPRs (loaded once,
// 32 coalesced dwordx4); spk broadcast via LDS; w3 staged in LDS; layer3
// as 144-thread partials + 9-thread reduce. Critical path ~700 cyc/step.
__global__ __launch_bounds__(256, 1) void recur_kernel(
    const float* __restrict__ h1s,  // [128][128]
    const float4* __restrict__ w2q, // [32][256] float4 cols: w2q[k4*256+j]
    const float* __restrict__ b2,
    const float* __restrict__ w3,   // [9][256]
    const float* __restrict__ b3,
    float* __restrict__ out) {      // [128][9]
  int b = blockIdx.x;
  int t = threadIdx.x;
  __shared__ float spk1s[128];
  __shared__ float spk2s[256];
  __shared__ float w3s[9 * 256];
  __shared__ float part[9][16];
  float4 w2c[32];
#pragma unroll
  for (int k4 = 0; k4 < 32; ++k4) w2c[k4] = w2q[k4 * 256 + t];
  for (int i = t; i < 9 * 256; i += 256) w3s[i] = w3[i];
  float h1 = (t < 128) ? h1s[b * 128 + t] : 0.f;
  float mem1 = 0.f, syn1 = 0.f, mem2 = 0.f, syn2 = 0.f;
  float b2v = b2[t];
  float mem3 = 0.f, syn3 = 0.f, pot = 0.f;
  float b3v = (t < 9) ? b3[t] : 0.f;
  int j3 = t >> 4, p = t & 15;      // layer3 partial owners (t < 144)
  __syncthreads();                  // w3s ready

  for (int step = 0; step < 10; ++step) {
    if (t < 128) {
      syn1 = ALPHA * syn1 + h1;
      mem1 = BETA * mem1 + syn1;
      float s = (mem1 > 1.0f) ? 1.0f : 0.0f;
      mem1 -= s;
      spk1s[t] = s;
    }
    __syncthreads();
    float h2 = b2v;
#pragma unroll
    for (int k4 = 0; k4 < 32; ++k4) {
      float4 s = *(const float4*)&spk1s[k4 * 4];   // broadcast read
      h2 = fmaf(s.x, w2c[k4].x, h2);
      h2 = fmaf(s.y, w2c[k4].y, h2);
      h2 = fmaf(s.z, w2c[k4].z, h2);
      h2 = fmaf(s.w, w2c[k4].w, h2);
    }
    syn2 = ALPHA * syn2 + h2;
    mem2 = BETA * mem2 + syn2;
    float s2 = (mem2 > 1.0f) ? 1.0f : 0.0f;
    mem2 -= s2;
    spk2s[t] = s2;
    __syncthreads();
    if (t < 144) {
      float a = 0.f;
      const float* wr = &w3s[j3 * 256 + p * 16];
      const float* sp = &spk2s[p * 16];
#pragma unroll
      for (int e = 0; e < 16; ++e) a = fmaf(sp[e], wr[e], a);
      part[j3][p] = a;
    }
    __syncthreads();
    if (t < 9) {
      float a = b3v;
#pragma unroll
      for (int p2 = 0; p2 < 16; ++p2) a += part[t][p2];
      syn3 = ALPHA * syn3 + a;
      mem3 = BETA * mem3 + syn3;
      pot += mem3;
    }
  }
  if (t < 9) out[b * 9 + t] = pot * 0.1f;
}

extern "C" void kernel_launch(void* const* d_in, const int* in_sizes, int n_in,
                              void* d_out, int out_size, void* d_ws, size_t ws_size,
                              hipStream_t stream) {
  const float* state   = (const float*)d_in[0];
  const float* history = (const float*)d_in[1];
  const float* cw1 = (const float*)d_in[2];
  const float* cb1 = (const float*)d_in[3];
  const float* cw2 = (const float*)d_in[4];
  const float* cb2 = (const float*)d_in[5];
  const float* cw3 = (const float*)d_in[6];
  const float* cb3 = (const float*)d_in[7];
  const float* w1  = (const float*)d_in[8];
  const float* b1  = (const float*)d_in[9];
  const float* w2  = (const float*)d_in[10];
  const float* b2  = (const float*)d_in[11];
  const float* w3  = (const float*)d_in[12];
  const float* b3  = (const float*)d_in[13];
  float* out = (float*)d_out;
  char* ws = (char*)d_ws;

  // workspace (bytes), time-multiplexed:
  //  f1  fp32 [0, 49,561,600)           conv1 -> conv2
  //    xb  [0, 18,923,520)              conv3 -> fc1   (f1 dead)
  //    w1p [18,923,520, 37,847,040)     pad_w1 (after conv2) -> fc1
  //  f2  fp32 [49,561,600, 71,712,768)  conv2 -> conv3
  //    P   [49,561,600, 68,501,504)     fc1 -> reduce  (f2 dead)
  //  small weights [71,712,768, 72,261,632)
  float* f1  = (float*)(ws + 0);
  float* xb  = (float*)(ws + 0);
  float* w1p = (float*)(ws + 18923520);
  float* f2  = (float*)(ws + 49561600);
  float* P   = (float*)(ws + 49561600);
  f16* wf1h = (f16*)(ws + 71712768);   // 12,288
  f16* wf1l = (f16*)(ws + 71725056);   // 12,288
  f16* wf2h = (f16*)(ws + 71737344);   // 65,536
  f16* wf2l = (f16*)(ws + 71802880);   // 65,536
  f16* wf3h = (f16*)(ws + 71868416);   // 98,304 (padded K=768)
  f16* wf3l = (f16*)(ws + 71966720);   // 98,304
  float* w2q = (float*)(ws + 72065024);  // 131,072
  float* h1s = (float*)(ws + 72196096);  // 65,536 (end 72,261,632)

  prep_weights_kernel<<<192, 256, 0, stream>>>(cw1, cw2, cw3, w2,
                                               wf1h, wf1l, wf2h, wf2l,
                                               wf3h, wf3l, w2q);
  // conv1: IC=3,KH=8,KWP=8,KWV=8,S=4, 224x224 -> 55x55(3025), OC=32, NPB=128
  direct_conv_kernel<3, 8, 8, 8, 4, 224, 224, 55, 3025, 32, 128, false>
      <<<dim3(24, 128), 256, 0, stream>>>(state, wf1h, wf1l, cb1, f1);
  // conv2: IC=32,KH=4,KWP=4,KWV=4,S=2, 55x55 -> 26x26(676), OC=64, NPB=64
  direct_conv_kernel<32, 4, 4, 4, 2, 55, 55, 26, 676, 64, 64, false>
      <<<dim3(11, 128), 256, 0, stream>>>(f1, wf2h, wf2l, cb2, f2);
  pad_w1_kernel<<<9240, 256, 0, stream>>>(w1, w1p);
  // conv3: IC=64,KH=3,KWP=4,KWV=3,S=1, 26x26 -> 24x24(576), OC=64, NPB=64 -> x
  direct_conv_kernel<64, 3, 4, 3, 1, 26, 26, 24, 576, 64, 64, true>
      <<<dim3(9, 128), 256, 0, stream>>>(f2, wf3h, wf3l, cb3, xb);
  histpack_kernel<<<48, 256, 0, stream>>>(history, xb);
  fc1_kernel<<<FC1_KT, 256, 0, stream>>>(xb, w1p, P);
  reduce_p_kernel<<<64, 256, 0, stream>>>(P, b1, h1s);
  recur_kernel<<<128, 256, 0, stream>>>(h1s, (const float4*)w2q, b2, w3, b3, out);
}

// Round 4
// 351.606 us; speedup vs baseline: 1.1941x; 1.1941x over previous
//
#include <hip/hip_runtime.h>

#define ALPHA 0.9f
#define BETA  0.8f
#define XS 36960   // padded row stride for x and w1p

typedef _Float16 f16;
typedef _Float16 f16x8 __attribute__((ext_vector_type(8)));
typedef float f32x4 __attribute__((ext_vector_type(4)));
typedef unsigned int u32;

// async global->LDS DMA, 16B per lane: per-lane global src, wave-uniform LDS
// base + lane*16 dest (m97 pattern).
#define GLOAD_LDS16(gsrc, ldst)                                        \
  __builtin_amdgcn_global_load_lds(                                    \
      (const __attribute__((address_space(1))) void*)(gsrc),           \
      (__attribute__((address_space(3))) void*)(ldst), 16, 0, 0)

// de-interleave (h,l)-pair dwords: hpair = h1<<16|h0, lpair = l1<<16|l0
__device__ inline u32 hpair(u32 d0, u32 d1) {
#if __has_builtin(__builtin_amdgcn_perm)
  return __builtin_amdgcn_perm(d1, d0, 0x05040100u);
#else
  return (d0 & 0xffffu) | (d1 << 16);
#endif
}
__device__ inline u32 lpair(u32 d0, u32 d1) {
#if __has_builtin(__builtin_amdgcn_perm)
  return __builtin_amdgcn_perm(d1, d0, 0x07060302u);
#else
  return (d0 >> 16) | (d1 & 0xffff0000u);
#endif
}

// split fp32 -> packed (h,l) f16-pair dword (exact same h/l values as the
// old consumer-side split: h=f16(v), l=f16(v-h))
__device__ inline u32 pack_hl(float v) {
  f16 h = (f16)v;
  f16 l = (f16)(v - (float)h);
  return (u32)__builtin_bit_cast(unsigned short, h) |
         ((u32)__builtin_bit_cast(unsigned short, l) << 16);
}

// ---------------------------------------------------------------------------
// state: 128x3x224x224  conv1 32x3x8x8 s4 -> f1hl (hl-pair) 128x32x55x55
// f1hl -> conv2 64x32x4x4 s2 -> f2hl (hl-pair) 128x64x26x26
// f2hl -> conv3 64x64x3x3 s1 -> x rows fp32 (36864 + 90 history, pad 36960)
// Convs: split-f16 MFMA (hi+lo, 3 MFMAs/product, fp32-quality: absmax 0.0).
// r13 (revert r11 direct-conv; back to r10 LDS-staged structure + two fixes):
//  1) activations stored as packed (h,l) f16-pair dwords, converted ONCE in
//     the producer epilogue -> conv2/conv3 staging is conversion-free copy
//     (was ~2x MFMA time of VALU per K-step, re-done at 3.6-7.7x reuse).
//  2) conv1 B staged via async global_load_lds width=16 (raw fp32, 16B-
//     aligned gathers), converted at fragment-read; removes the VGPR round
//     trip and keeps ~4KB/wave of loads in flight (r10/r11 had MLP~2).
// ---------------------------------------------------------------------------

// Split conv weights into f16 hi/lo pairs; conv3 padded [oc][c][kh][4]
// (kw=3 -> 0). Repack w2 (256x128) -> w2q[k4][j] float4 columns.
__global__ __launch_bounds__(256) void prep_weights_kernel(
    const float* __restrict__ cw1, const float* __restrict__ cw2,
    const float* __restrict__ cw3, const float* __restrict__ w2,
    f16* __restrict__ w1h, f16* __restrict__ w1l,
    f16* __restrict__ w2h, f16* __restrict__ w2l,
    f16* __restrict__ w3h, f16* __restrict__ w3l,
    float* __restrict__ w2q) {
  int i = blockIdx.x * 256 + threadIdx.x;   // grid covers 49152
  if (i < 6144)  { float v = cw1[i]; f16 h = (f16)v; w1h[i] = h; w1l[i] = (f16)(v - (float)h); }
  if (i < 32768) { float v = cw2[i]; f16 h = (f16)v; w2h[i] = h; w2l[i] = (f16)(v - (float)h); }
  if (i < 49152) {
    int oc = i / 768, r = i % 768;
    int c = r / 12, rr = r % 12, kh = rr >> 2, kw = rr & 3;
    float v = (kw < 3) ? cw3[oc * 576 + c * 9 + kh * 3 + kw] : 0.f;
    f16 h = (f16)v; w3h[i] = h; w3l[i] = (f16)(v - (float)h);
  }
  if (i < 32768) {   // w2[j][k] -> w2q[(k4*256 + j)*4 + e]
    int j = i >> 7, k = i & 127;
    w2q[((k >> 2) * 256 + j) * 4 + (k & 3)] = w2[i];
  }
}

// Copy w1 (128 x 36954) into padded rows (128 x 36960), zero tail.
__global__ __launch_bounds__(256) void pad_w1_kernel(
    const float* __restrict__ w1, float* __restrict__ w1p) {
  int i = blockIdx.x * 256 + threadIdx.x;   // float2 slots: 128 * 18480
  if (i < 128 * 18480) {
    int j = i / 18480, c = i - j * 18480;
    float2 v;
    if (c < 18477) v = *(const float2*)&w1[(size_t)j * 36954 + c * 2];
    else v = make_float2(0.f, 0.f);
    *(float2*)&w1p[(size_t)j * XS + c * 2] = v;
  }
}

// ---------------------------------------------------------------------------
// conv1: 16x16x32 MFMA layouts (HW-verified): A[m=lane&15][k=quad*8+j],
// B[k=quad*8+j][n=lane&15], C col=lane&15 row=quad*4+reg.
// B slot s (0..511): holds B[k=kt*32+((s>>4)&3)*8+j][npos=(s>>6)*16+(s&15)],
// raw fp32, staged by global_load_lds: instr (si=s>>8, w=(s>>6)&3, half):
// lane l -> slot si*256+w*64+l, LDS float idx (s>>6)*512 + half*256 + (s&63)*4.
// Gathers are 16B-aligned (ow*4 floats, row 224 floats). Convert to split-f16
// at fragment read (WOC=1: each slot read once -> same convert count).
// ---------------------------------------------------------------------------
__global__ __launch_bounds__(256) void conv1_kernel(
    const float* __restrict__ in, const f16* __restrict__ wh,
    const f16* __restrict__ wl, const float* __restrict__ bias,
    u32* __restrict__ out) {
  constexpr int K = 192, KCH = 6, OW = 55, OHW = 3025, NPB = 128;
  __shared__ __attribute__((aligned(16))) f16 Ah[2 * 512], Al[2 * 512]; // 4KB
  __shared__ __attribute__((aligned(16))) float Bf[8 * 512];            // 16KB

  const int n = blockIdx.y, pos0 = blockIdx.x * NPB;
  const int t = threadIdx.x;
  const int w = t >> 6, lane = t & 63, quad = lane >> 4, l16 = lane & 15;
  const float* __restrict__ inb = in + (size_t)n * 3 * 224 * 224;

  // staging invariants: rq = filter-row offset within kt (same for both si)
  const int rq = (t >> 4) & 3;
  int base[2];
#pragma unroll
  for (int si = 0; si < 2; ++si) {
    int s = t + si * 256;
    int pos = pos0 + (s >> 6) * 16 + (s & 15);
    if (pos > OHW - 1) pos = OHW - 1;      // clamp (store masked later)
    int oh = pos / OW, ow = pos - oh * OW;
    base[si] = oh * 4 * 224 + ow * 4;
  }
  // A slot (t<128): oc am, k offset ak
  const int am = (t >> 6) * 16 + (t & 15);
  const int ak = ((t >> 4) & 3) * 8;

  int posv[2];
#pragma unroll
  for (int ntl = 0; ntl < 2; ++ntl)
    posv[ntl] = pos0 + (w * 2 + ntl) * 16 + l16;

  f32x4 acc[2][2] = {};

  for (int kt = 0; kt < KCH; ++kt) {
    __syncthreads();
    if (t < 128) {   // stage weights (tiny, plain)
      *(f16x8*)&Ah[t * 8] = *(const f16x8*)&wh[am * K + kt * 32 + ak];
      *(f16x8*)&Al[t * 8] = *(const f16x8*)&wl[am * K + kt * 32 + ak];
    }
    {  // async B staging: 4 global_load_lds per wave
      int r = kt * 4 + rq;
      int c = r >> 3, kh = r & 7;
      int rowoff = c * 50176 + kh * 224;
#pragma unroll
      for (int si = 0; si < 2; ++si)
#pragma unroll
        for (int half = 0; half < 2; ++half)
          GLOAD_LDS16(inb + rowoff + base[si] + half * 4,
                      &Bf[(si * 4 + w) * 512 + half * 256]);
    }
    __syncthreads();   // drains vmcnt: B in LDS, A visible

    f16x8 ah0 = *(const f16x8*)&Ah[0 * 512 + lane * 8];
    f16x8 ah1 = *(const f16x8*)&Ah[1 * 512 + lane * 8];
    f16x8 al0 = *(const f16x8*)&Al[0 * 512 + lane * 8];
    f16x8 al1 = *(const f16x8*)&Al[1 * 512 + lane * 8];
    f16x8 bh[2], bl[2];
#pragma unroll
    for (int ntl = 0; ntl < 2; ++ntl) {
      const float* bp = &Bf[(w * 2 + ntl) * 512 + lane * 4];
      float4 v0 = *(const float4*)bp;
      float4 v1 = *(const float4*)(bp + 256);
      float vv[8] = {v0.x, v0.y, v0.z, v0.w, v1.x, v1.y, v1.z, v1.w};
#pragma unroll
      for (int e = 0; e < 8; ++e) {
        f16 h = (f16)vv[e];
        bh[ntl][e] = h;
        bl[ntl][e] = (f16)(vv[e] - (float)h);
      }
    }
    acc[0][0] = __builtin_amdgcn_mfma_f32_16x16x32_f16(ah0, bh[0], acc[0][0], 0, 0, 0);
    acc[0][0] = __builtin_amdgcn_mfma_f32_16x16x32_f16(ah0, bl[0], acc[0][0], 0, 0, 0);
    acc[0][0] = __builtin_amdgcn_mfma_f32_16x16x32_f16(al0, bh[0], acc[0][0], 0, 0, 0);
    acc[1][0] = __builtin_amdgcn_mfma_f32_16x16x32_f16(ah1, bh[0], acc[1][0], 0, 0, 0);
    acc[1][0] = __builtin_amdgcn_mfma_f32_16x16x32_f16(ah1, bl[0], acc[1][0], 0, 0, 0);
    acc[1][0] = __builtin_amdgcn_mfma_f32_16x16x32_f16(al1, bh[0], acc[1][0], 0, 0, 0);
    acc[0][1] = __builtin_amdgcn_mfma_f32_16x16x32_f16(ah0, bh[1], acc[0][1], 0, 0, 0);
    acc[0][1] = __builtin_amdgcn_mfma_f32_16x16x32_f16(ah0, bl[1], acc[0][1], 0, 0, 0);
    acc[0][1] = __builtin_amdgcn_mfma_f32_16x16x32_f16(al0, bh[1], acc[0][1], 0, 0, 0);
    acc[1][1] = __builtin_amdgcn_mfma_f32_16x16x32_f16(ah1, bh[1], acc[1][1], 0, 0, 0);
    acc[1][1] = __builtin_amdgcn_mfma_f32_16x16x32_f16(ah1, bl[1], acc[1][1], 0, 0, 0);
    acc[1][1] = __builtin_amdgcn_mfma_f32_16x16x32_f16(al1, bh[1], acc[1][1], 0, 0, 0);
  }

#pragma unroll
  for (int mtl = 0; mtl < 2; ++mtl)
#pragma unroll
    for (int ntl = 0; ntl < 2; ++ntl)
#pragma unroll
      for (int r = 0; r < 4; ++r) {
        int oc  = mtl * 16 + quad * 4 + r;
        int pos = posv[ntl];
        if (pos < OHW) {
          float v = acc[mtl][ntl][r] + bias[oc];
          v = v > 0.f ? v : 0.f;
          out[((size_t)n * 32 + oc) * OHW + pos] = pack_hl(v);
        }
      }
}

// ---------------------------------------------------------------------------
// conv2/conv3: input is packed (h,l)-pair dwords -> staging is a pure dword
// copy (8 independent loads/thread, no conversion), de-interleave at
// fragment read via v_perm (2 ops per pair). OC=64, NPB=64: MTILES=NTILES=4,
// WOC=2 (waves {0,1} oc-half, {2,3}; wpos = w>>1).
// ---------------------------------------------------------------------------
template<int IC, int KH, int KWP, int KWV, int S, int IH, int IW,
         int OW, int OHW, int OC, int NPB, bool OUT_X>
__global__ __launch_bounds__(256) void convhl_kernel(
    const u32* __restrict__ in, const f16* __restrict__ wh,
    const f16* __restrict__ wl, const float* __restrict__ bias,
    void* __restrict__ outv) {
  constexpr int K = IC * KH * KWP;      // 512 / 768
  constexpr int KCH = K / 32;           // 16 / 24
  __shared__ __attribute__((aligned(16))) f16 Ah[4 * 512], Al[4 * 512]; // 8KB
  __shared__ __attribute__((aligned(16))) u32 Bhl[2][256 * 4];          // 8KB

  const int n = blockIdx.y, pos0 = blockIdx.x * NPB;
  const int t = threadIdx.x;
  const int w = t >> 6, lane = t & 63, quad = lane >> 4, l16 = lane & 15;
  const int woc = w & 1, wpos = w >> 1;
  const u32* __restrict__ inb = in + (size_t)n * IC * IH * IW;

  // B slot s = t: npos = (t>>6)*16 + (t&15); k-rows kt*8 + rq + half
  int pos = pos0 + (t >> 6) * 16 + (t & 15);
  if (pos > OHW - 1) pos = OHW - 1;      // clamp (store masked later)
  int oh = pos / OW, ow = pos - oh * OW;
  const int ohS = oh * S, owS = ow * S;
  const int rq = ((t >> 4) & 3) * 2;
  const int am = (t >> 6) * 16 + (t & 15);
  const int ak = ((t >> 4) & 3) * 8;

  int posv[2];
#pragma unroll
  for (int ntl = 0; ntl < 2; ++ntl)
    posv[ntl] = pos0 + (wpos * 2 + ntl) * 16 + l16;

  f32x4 acc[2][2] = {};

  for (int kt = 0; kt < KCH; ++kt) {
    __syncthreads();
    // stage weights: 8 consecutive k for one oc (all 256 threads)
    *(f16x8*)&Ah[t * 8] = *(const f16x8*)&wh[am * K + kt * 32 + ak];
    *(f16x8*)&Al[t * 8] = *(const f16x8*)&wl[am * K + kt * 32 + ak];
    // stage B: pure hl-dword gather, 4 dwords per half
#pragma unroll
    for (int half = 0; half < 2; ++half) {
      int row = kt * 8 + rq + half;
      int c = row / KH, kh = row - c * KH;
      const u32* p = inb + ((size_t)c * IH + ohS + kh) * IW + owS;
      uint4 d;
      d.x = p[0]; d.y = p[1]; d.z = p[2];
      d.w = (KWV < KWP) ? 0u : p[3];       // conv3: padded kw=3 -> 0
      *(uint4*)&Bhl[half][t * 4] = d;
    }
    __syncthreads();

    f16x8 ah0 = *(const f16x8*)&Ah[(woc * 2 + 0) * 512 + lane * 8];
    f16x8 ah1 = *(const f16x8*)&Ah[(woc * 2 + 1) * 512 + lane * 8];
    f16x8 al0 = *(const f16x8*)&Al[(woc * 2 + 0) * 512 + lane * 8];
    f16x8 al1 = *(const f16x8*)&Al[(woc * 2 + 1) * 512 + lane * 8];
    f16x8 bh[2], bl[2];
#pragma unroll
    for (int ntl = 0; ntl < 2; ++ntl) {
      int sl = ((wpos * 2 + ntl) * 64 + lane) * 4;
      uint4 q0 = *(const uint4*)&Bhl[0][sl];
      uint4 q1 = *(const uint4*)&Bhl[1][sl];
      uint4 hv, lv;
      hv.x = hpair(q0.x, q0.y); lv.x = lpair(q0.x, q0.y);
      hv.y = hpair(q0.z, q0.w); lv.y = lpair(q0.z, q0.w);
      hv.z = hpair(q1.x, q1.y); lv.z = lpair(q1.x, q1.y);
      hv.w = hpair(q1.z, q1.w); lv.w = lpair(q1.z, q1.w);
      bh[ntl] = __builtin_bit_cast(f16x8, hv);
      bl[ntl] = __builtin_bit_cast(f16x8, lv);
    }
    acc[0][0] = __builtin_amdgcn_mfma_f32_16x16x32_f16(ah0, bh[0], acc[0][0], 0, 0, 0);
    acc[0][0] = __builtin_amdgcn_mfma_f32_16x16x32_f16(ah0, bl[0], acc[0][0], 0, 0, 0);
    acc[0][0] = __builtin_amdgcn_mfma_f32_16x16x32_f16(al0, bh[0], acc[0][0], 0, 0, 0);
    acc[1][0] = __builtin_amdgcn_mfma_f32_16x16x32_f16(ah1, bh[0], acc[1][0], 0, 0, 0);
    acc[1][0] = __builtin_amdgcn_mfma_f32_16x16x32_f16(ah1, bl[0], acc[1][0], 0, 0, 0);
    acc[1][0] = __builtin_amdgcn_mfma_f32_16x16x32_f16(al1, bh[0], acc[1][0], 0, 0, 0);
    acc[0][1] = __builtin_amdgcn_mfma_f32_16x16x32_f16(ah0, bh[1], acc[0][1], 0, 0, 0);
    acc[0][1] = __builtin_amdgcn_mfma_f32_16x16x32_f16(ah0, bl[1], acc[0][1], 0, 0, 0);
    acc[0][1] = __builtin_amdgcn_mfma_f32_16x16x32_f16(al0, bh[1], acc[0][1], 0, 0, 0);
    acc[1][1] = __builtin_amdgcn_mfma_f32_16x16x32_f16(ah1, bh[1], acc[1][1], 0, 0, 0);
    acc[1][1] = __builtin_amdgcn_mfma_f32_16x16x32_f16(ah1, bl[1], acc[1][1], 0, 0, 0);
    acc[1][1] = __builtin_amdgcn_mfma_f32_16x16x32_f16(al1, bh[1], acc[1][1], 0, 0, 0);
  }

#pragma unroll
  for (int mtl = 0; mtl < 2; ++mtl)
#pragma unroll
    for (int ntl = 0; ntl < 2; ++ntl)
#pragma unroll
      for (int r = 0; r < 4; ++r) {
        int oc = (woc * 2 + mtl) * 16 + quad * 4 + r;
        int p2 = posv[ntl];
        if (p2 < OHW) {
          float v = acc[mtl][ntl][r] + bias[oc];
          v = v > 0.f ? v : 0.f;
          if constexpr (OUT_X)
            ((float*)outv)[(size_t)n * XS + oc * OHW + p2] = v;
          else
            ((u32*)outv)[((size_t)n * OC + oc) * OHW + p2] = pack_hl(v);
        }
      }
}

// history -> x[:, 36864:36954], zero the pad to 36960
__global__ __launch_bounds__(256) void histpack_kernel(
    const float* __restrict__ h, float* __restrict__ x) {
  int i = blockIdx.x * 256 + threadIdx.x;
  if (i < 128 * 96) {
    int n = i / 96, k = i % 96;
    x[(size_t)n * XS + 36864 + k] = (k < 90) ? h[n * 90 + k] : 0.f;
  }
}

// FC1 (fp32): register-blocked split-K GEMM, 128b x 128j tile per block,
// thread owns 8x8 interleaved sub-tile. P[kt][b][j] deterministic partials.
#define FC1_KT 289
__global__ __launch_bounds__(256) void fc1_kernel(
    const float* __restrict__ x, const float* __restrict__ w1p,
    float* __restrict__ P) {
  int kt = blockIdx.x;        // 0..288
  int t  = threadIdx.x;
  int bq = t & 15, jq = t >> 4;
  __shared__ float xs[128 * 36];
  __shared__ float wsm[128 * 36];
  float acc[8][8];
#pragma unroll
  for (int bb = 0; bb < 8; ++bb)
#pragma unroll
    for (int jj = 0; jj < 8; ++jj) acc[bb][jj] = 0.f;

  int cs = t & 7;          // float4 column for staging (0..7)
  int rs = t >> 3;         // row base for staging (0..31), 4 passes
#pragma unroll 1
  for (int s = 0; s < 4; ++s) {
    int k0 = kt * 128 + s * 32;
    __syncthreads();
#pragma unroll
    for (int p = 0; p < 4; ++p) {
      int r = rs + p * 32;
      int gk = k0 + cs * 4;
      float4 xv, wv;
      if (gk < 36954) {
        xv = *(const float4*)&x[(size_t)r * XS + gk];
        wv = *(const float4*)&w1p[(size_t)r * XS + gk];
      } else {
        xv = make_float4(0.f, 0.f, 0.f, 0.f);
        wv = make_float4(0.f, 0.f, 0.f, 0.f);
      }
      *(float4*)&xs[r * 36 + cs * 4] = xv;
      *(float4*)&wsm[r * 36 + cs * 4] = wv;
    }
    __syncthreads();
#pragma unroll 1
    for (int kk = 0; kk < 32; kk += 4) {
      float4 xv[8], wv[8];
#pragma unroll
      for (int i = 0; i < 8; ++i)
        xv[i] = *(const float4*)&xs[(bq + 16 * i) * 36 + kk];
#pragma unroll
      for (int i = 0; i < 8; ++i)
        wv[i] = *(const float4*)&wsm[(jq + 16 * i) * 36 + kk];
#pragma unroll
      for (int bb = 0; bb < 8; ++bb)
#pragma unroll
        for (int jj = 0; jj < 8; ++jj) {
          acc[bb][jj] = fmaf(xv[bb].x, wv[jj].x, acc[bb][jj]);
          acc[bb][jj] = fmaf(xv[bb].y, wv[jj].y, acc[bb][jj]);
          acc[bb][jj] = fmaf(xv[bb].z, wv[jj].z, acc[bb][jj]);
          acc[bb][jj] = fmaf(xv[bb].w, wv[jj].w, acc[bb][jj]);
        }
    }
  }
  float* Pb = P + (size_t)kt * 16384;
#pragma unroll
  for (int bb = 0; bb < 8; ++bb)
#pragma unroll
    for (int jj = 0; jj < 8; ++jj)
      Pb[(bq + 16 * bb) * 128 + jq + 16 * jj] = acc[bb][jj];
}

// Reduce P over kt: h1s[b][j] = sum_kt P[kt][b][j] + b1[j].
__global__ __launch_bounds__(256) void reduce_p_kernel(
    const float* __restrict__ P, const float* __restrict__ b1,
    float* __restrict__ h1s) {
  int idx = blockIdx.x * 256 + threadIdx.x;   // 0..16383
  int j = idx & 127;
  float a0 = 0.f, a1 = 0.f, a2 = 0.f, a3 = 0.f;
  int kt = 0;
#pragma unroll 2
  for (; kt + 3 < FC1_KT; kt += 4) {
    a0 += P[(size_t)(kt + 0) * 16384 + idx];
    a1 += P[(size_t)(kt + 1) * 16384 + idx];
    a2 += P[(size_t)(kt + 2) * 16384 + idx];
    a3 += P[(size_t)(kt + 3) * 16384 + idx];
  }
  for (; kt < FC1_KT; ++kt) a0 += P[(size_t)kt * 16384 + idx];
  h1s[idx] = ((a0 + a1) + (a2 + a3)) + b1[j];
}

// Recurrence: one block per batch row. w2 column in VGPRs (loaded once,
// 32 coalesced dwordx4); spk broadcast via LDS; w3 staged in LDS; layer3
// as 144-thread partials + 9-thread reduce. Critical path ~700 cyc/step.
__global__ __launch_bounds__(256, 1) void recur_kernel(
    const float* __restrict__ h1s,  // [128][128]
    const float4* __restrict__ w2q, // [32][256] float4 cols: w2q[k4*256+j]
    const float* __restrict__ b2,
    const float* __restrict__ w3,   // [9][256]
    const float* __restrict__ b3,
    float* __restrict__ out) {      // [128][9]
  int b = blockIdx.x;
  int t = threadIdx.x;
  __shared__ float spk1s[128];
  __shared__ float spk2s[256];
  __shared__ float w3s[9 * 256];
  __shared__ float part[9][16];
  float4 w2c[32];
#pragma unroll
  for (int k4 = 0; k4 < 32; ++k4) w2c[k4] = w2q[k4 * 256 + t];
  for (int i = t; i < 9 * 256; i += 256) w3s[i] = w3[i];
  float h1 = (t < 128) ? h1s[b * 128 + t] : 0.f;
  float mem1 = 0.f, syn1 = 0.f, mem2 = 0.f, syn2 = 0.f;
  float b2v = b2[t];
  float mem3 = 0.f, syn3 = 0.f, pot = 0.f;
  float b3v = (t < 9) ? b3[t] : 0.f;
  int j3 = t >> 4, p = t & 15;      // layer3 partial owners (t < 144)
  __syncthreads();                  // w3s ready

  for (int step = 0; step < 10; ++step) {
    if (t < 128) {
      syn1 = ALPHA * syn1 + h1;
      mem1 = BETA * mem1 + syn1;
      float s = (mem1 > 1.0f) ? 1.0f : 0.0f;
      mem1 -= s;
      spk1s[t] = s;
    }
    __syncthreads();
    float h2 = b2v;
#pragma unroll
    for (int k4 = 0; k4 < 32; ++k4) {
      float4 s = *(const float4*)&spk1s[k4 * 4];   // broadcast read
      h2 = fmaf(s.x, w2c[k4].x, h2);
      h2 = fmaf(s.y, w2c[k4].y, h2);
      h2 = fmaf(s.z, w2c[k4].z, h2);
      h2 = fmaf(s.w, w2c[k4].w, h2);
    }
    syn2 = ALPHA * syn2 + h2;
    mem2 = BETA * mem2 + syn2;
    float s2 = (mem2 > 1.0f) ? 1.0f : 0.0f;
    mem2 -= s2;
    spk2s[t] = s2;
    __syncthreads();
    if (t < 144) {
      float a = 0.f;
      const float* wr = &w3s[j3 * 256 + p * 16];
      const float* sp = &spk2s[p * 16];
#pragma unroll
      for (int e = 0; e < 16; ++e) a = fmaf(sp[e], wr[e], a);
      part[j3][p] = a;
    }
    __syncthreads();
    if (t < 9) {
      float a = b3v;
#pragma unroll
      for (int p2 = 0; p2 < 16; ++p2) a += part[t][p2];
      syn3 = ALPHA * syn3 + a;
      mem3 = BETA * mem3 + syn3;
      pot += mem3;
    }
  }
  if (t < 9) out[b * 9 + t] = pot * 0.1f;
}

extern "C" void kernel_launch(void* const* d_in, const int* in_sizes, int n_in,
                              void* d_out, int out_size, void* d_ws, size_t ws_size,
                              hipStream_t stream) {
  const float* state   = (const float*)d_in[0];
  const float* history = (const float*)d_in[1];
  const float* cw1 = (const float*)d_in[2];
  const float* cb1 = (const float*)d_in[3];
  const float* cw2 = (const float*)d_in[4];
  const float* cb2 = (const float*)d_in[5];
  const float* cw3 = (const float*)d_in[6];
  const float* cb3 = (const float*)d_in[7];
  const float* w1  = (const float*)d_in[8];
  const float* b1  = (const float*)d_in[9];
  const float* w2  = (const float*)d_in[10];
  const float* b2  = (const float*)d_in[11];
  const float* w3  = (const float*)d_in[12];
  const float* b3  = (const float*)d_in[13];
  float* out = (float*)d_out;
  char* ws = (char*)d_ws;

  // workspace (bytes), time-multiplexed:
  //  f1hl  [0, 49,561,600)              conv1 -> conv2  (hl-pair dwords)
  //    xb  [0, 18,923,520)              conv3 -> fc1    (f1hl dead)
  //    w1p [18,923,520, 37,847,040)     pad_w1 (after conv2) -> fc1
  //  f2hl  [49,561,600, 71,712,768)     conv2 -> conv3  (hl-pair dwords)
  //    P   [49,561,600, 68,501,504)     fc1 -> reduce   (f2hl dead)
  //  small weights [71,712,768, 72,261,632)
  u32*   f1hl = (u32*)(ws + 0);
  float* xb   = (float*)(ws + 0);
  float* w1p  = (float*)(ws + 18923520);
  u32*   f2hl = (u32*)(ws + 49561600);
  float* P    = (float*)(ws + 49561600);
  f16* wf1h = (f16*)(ws + 71712768);   // 12,288
  f16* wf1l = (f16*)(ws + 71725056);   // 12,288
  f16* wf2h = (f16*)(ws + 71737344);   // 65,536
  f16* wf2l = (f16*)(ws + 71802880);   // 65,536
  f16* wf3h = (f16*)(ws + 71868416);   // 98,304 (padded K=768)
  f16* wf3l = (f16*)(ws + 71966720);   // 98,304
  float* w2q = (float*)(ws + 72065024);  // 131,072
  float* h1s = (float*)(ws + 72196096);  // 65,536 (end 72,261,632)

  prep_weights_kernel<<<192, 256, 0, stream>>>(cw1, cw2, cw3, w2,
                                               wf1h, wf1l, wf2h, wf2l,
                                               wf3h, wf3l, w2q);
  // conv1: 224x224 -> 55x55(3025), OC=32, NPB=128, async-LDS staged
  conv1_kernel<<<dim3(24, 128), 256, 0, stream>>>(state, wf1h, wf1l, cb1, f1hl);
  // conv2: IC=32,KH=4,KWP=4,KWV=4,S=2, 55x55 -> 26x26(676), OC=64, NPB=64
  convhl_kernel<32, 4, 4, 4, 2, 55, 55, 26, 676, 64, 64, false>
      <<<dim3(11, 128), 256, 0, stream>>>(f1hl, wf2h, wf2l, cb2, (void*)f2hl);
  pad_w1_kernel<<<9240, 256, 0, stream>>>(w1, w1p);
  // conv3: IC=64,KH=3,KWP=4,KWV=3,S=1, 26x26 -> 24x24(576), OC=64, NPB=64 -> x
  convhl_kernel<64, 3, 4, 3, 1, 26, 26, 24, 576, 64, 64, true>
      <<<dim3(9, 128), 256, 0, stream>>>(f2hl, wf3h, wf3l, cb3, (void*)xb);
  histpack_kernel<<<48, 256, 0, stream>>>(history, xb);
  fc1_kernel<<<FC1_KT, 256, 0, stream>>>(xb, w1p, P);
  reduce_p_kernel<<<64, 256, 0, stream>>>(P, b1, h1s);
  recur_kernel<<<128, 256, 0, stream>>>(h1s, (const float4*)w2q, b2, w3, b3, out);
}